// Round 13
// baseline (390.554 us; speedup 1.0000x reference)
//
#include <hip/hip_runtime.h>
#include <hip/hip_bf16.h>
#include <hip/hip_fp16.h>

#define WPB 4          // waves per block (256 threads)
#define SCAN_EPB 1024  // elements per scan block (256 thr x 4)

// counting-sort CSR build (replaces scattered-atomic hist+rank+place):
#define CSB 384        // blocks in coarse hist/place passes (nP = CSB*nbuckets must stay < 1M for scan chain)
#define BSH 7          // bucket shift: 128 nodes per coarse bucket
#define BWID 128       // 1 << BSH

typedef _Float16 h8 __attribute__((ext_vector_type(8)));
typedef float f32x4 __attribute__((ext_vector_type(4)));

__device__ __forceinline__ float bcast(float v, int i) {
  return __builtin_bit_cast(float, __builtin_amdgcn_readlane(__builtin_bit_cast(int, v), i));
}
__device__ __forceinline__ h8 h8zero() {
  h8 r;
#pragma unroll
  for (int j = 0; j < 8; ++j) r[j] = (_Float16)0;
  return r;
}
__device__ __forceinline__ h8 cvt8(float4 a, float4 b) {
  h8 r;
  r[0] = (_Float16)a.x; r[1] = (_Float16)a.y; r[2] = (_Float16)a.z; r[3] = (_Float16)a.w;
  r[4] = (_Float16)b.x; r[5] = (_Float16)b.y; r[6] = (_Float16)b.z; r[7] = (_Float16)b.w;
  return r;
}

// ---------------- encoders (MFMA layer 2) ----------------
// out = tanh(x @ W1^T + b1) @ W2^T + b2.
// Layer 1: f32 scalar, lane = hidden feature. Layer 2: 8x mfma_16x16x32_f16
// per 16-row group against pre-converted W2 fragments; b2 folded into C-init.
// Hidden goes through a per-wave XOR-swizzled LDS transpose (chunk ^= row&7
// keeps writes and b128 reads <=2-way bank aliasing = free, m136).
// Grid stays CAPPED (2048): the W->VGPR preamble replicates per block.
template<int IN_F>
__global__ __launch_bounds__(256, 4) void encoder_mfma_kernel(
    const float* __restrict__ x,
    const float* __restrict__ W1, const float* __restrict__ b1,
    const h8* __restrict__ W2h, const float* __restrict__ b2,
    __half* __restrict__ out, int n_rows) {
  __shared__ _Float16 hlds[WPB][16][64];
  int t = threadIdx.x;
  int wave = t >> 6, lane = t & 63;
  int mm = lane & 15, fb = lane >> 4;

  float w1reg[IN_F];
#pragma unroll
  for (int j = 0; j < IN_F; ++j) w1reg[j] = W1[lane * IN_F + j];
  float b1v = b1[lane];

  h8 Bf[4][2];
  float bvt[4];
#pragma unroll
  for (int tt = 0; tt < 4; ++tt) {
#pragma unroll
    for (int s = 0; s < 2; ++s) Bf[tt][s] = W2h[(tt * 2 + s) * 64 + lane];
    bvt[tt] = b2[16 * tt + mm];
  }

  // swizzled 16B-chunk offsets for the A-fragment reads (row = mm)
  int c0 = ((fb ^ (mm & 7)) << 3);        // logical k in [8fb, 8fb+8)
  int c1 = (((4 + fb) ^ (mm & 7)) << 3);  // logical k in [32+8fb, 32+8fb+8)

  const int ntot = n_rows * IN_F;
  int stride16 = gridDim.x * WPB * 16;
  for (int rowb = (blockIdx.x * WPB + wave) * 16; rowb < n_rows; rowb += stride16) {
    int base = rowb * IN_F;
    float xa = 0.0f, xb = 0.0f;
    if (base + lane < ntot) xa = x[base + lane];
    if (base + 64 + lane < ntot) xb = x[base + 64 + lane];

#pragma unroll
    for (int r = 0; r < 16; ++r) {
      float h = b1v;
#pragma unroll
      for (int j = 0; j < IN_F; ++j) {
        int idx = r * IN_F + j;  // compile-time after unroll
        float xv;
        if (idx < 64) xv = bcast(xa, idx); else xv = bcast(xb, idx - 64);
        h += w1reg[j] * xv;
      }
      int sc = ((((lane >> 3) ^ (r & 7)) << 3) | (lane & 7));
      hlds[wave][r][sc] = (_Float16)tanhf(h);
    }

    // per-wave LDS slice: within-wave ds_write->ds_read ordering is handled
    // by compiler-inserted lgkmcnt; no barrier needed.
    h8 a0 = *(const h8*)&hlds[wave][mm][c0];
    h8 a1 = *(const h8*)&hlds[wave][mm][c1];

    f32x4 d[4];
#pragma unroll
    for (int tt = 0; tt < 4; ++tt) {
      f32x4 dz; dz[0] = bvt[tt]; dz[1] = bvt[tt]; dz[2] = bvt[tt]; dz[3] = bvt[tt];
      d[tt] = __builtin_amdgcn_mfma_f32_16x16x32_f16(a0, Bf[tt][0], dz, 0, 0, 0);
      d[tt] = __builtin_amdgcn_mfma_f32_16x16x32_f16(a1, Bf[tt][1], d[tt], 0, 0, 0);
    }

    // D: col = lane&15 (mm), row = fb*4 + reg (m89)
#pragma unroll
    for (int i = 0; i < 4; ++i) {
      int grow = rowb + fb * 4 + i;
      if (grow < n_rows) {
#pragma unroll
        for (int tt = 0; tt < 4; ++tt)
          out[(size_t)grow * 64 + 16 * tt + mm] = __float2half(d[tt][i]);
      }
    }
  }
}

// ---------------- CSR build: two-level counting sort, NO global atomics ----------------
// Counting sort by dest with LDS atomics + streaming I/O (the old scattered-
// atomic hist ran at the ~26 G atomics/s floor, 106 us). Rank order within a
// dest is arbitrary, so any entry->slot bijection is valid.

__global__ __launch_bounds__(256) void bucket_hist_kernel(
    const int* __restrict__ ev, const int* __restrict__ ec,
    int* __restrict__ partial, int n_edges, int n_vars, int nbuckets) {
  extern __shared__ int cnt[];
  int t = threadIdx.x;
  for (int i = t; i < nbuckets; i += 256) cnt[i] = 0;
  __syncthreads();
  int chunk = (n_edges + CSB - 1) / CSB;
  int lo = blockIdx.x * chunk;
  int hi = lo + chunk; if (hi > n_edges) hi = n_edges;
  for (int e = lo + t; e < hi; e += 256) {
    int v = ev[e], c = ec[e];
    atomicAdd(&cnt[v >> BSH], 1);
    atomicAdd(&cnt[(n_vars + c) >> BSH], 1);
  }
  __syncthreads();
  // bucket-major layout so one exclusive scan yields global slot bases
  for (int i = t; i < nbuckets; i += 256)
    partial[(size_t)i * CSB + blockIdx.x] = cnt[i];
}

// Coarse place: LDS cursors start at this block's scanned bases; entries are
// written grouped by coarse bucket. keypay packs (key & 127)<<25 | payload
// (payload < 2^25: node ids <= 200k).
__global__ __launch_bounds__(256) void bucket_place_kernel(
    const int* __restrict__ ev, const int* __restrict__ ec,
    const int* __restrict__ scanned, unsigned int* __restrict__ keypay,
    int n_edges, int n_vars, int nbuckets) {
  extern __shared__ int cur[];
  int t = threadIdx.x;
  for (int i = t; i < nbuckets; i += 256)
    cur[i] = scanned[(size_t)i * CSB + blockIdx.x];
  __syncthreads();
  int chunk = (n_edges + CSB - 1) / CSB;  // MUST match bucket_hist_kernel
  int lo = blockIdx.x * chunk;
  int hi = lo + chunk; if (hi > n_edges) hi = n_edges;
  for (int e = lo + t; e < hi; e += 256) {
    int v = ev[e], c = ec[e];
    int mc = n_vars + c;
    int s1 = atomicAdd(&cur[v >> BSH], 1);
    keypay[s1] = ((unsigned)(v & (BWID - 1)) << 25) | (unsigned)c;
    int s2 = atomicAdd(&cur[mc >> BSH], 1);
    keypay[s2] = ((unsigned)(mc & (BWID - 1)) << 25) | (unsigned)v;
  }
}

// Fine pass: one block per coarse bucket (contiguous segment of keypay).
// Builds the exact 128-node sub-CSR in LDS, emits rp + esrc coalesced.
// Block 0 also zero-fills the two 128-B tail rows (zrow) of h_var/h_con.
// R13: also emits the degree-balanced perm FOR FREE -- ranks the bucket's
// 128 nodes by degree (descending) in LDS (O(128^2)/block ~ 640 cy) and
// writes perm[subgroup_base + rank] = node. A 16-row wave group then draws
// from a sorted window of 128 Poisson samples (max16 ~= mean16), keeping
// R11/R12's balance gain without the 5-dispatch global degree sort chain.
// Var/con subgroups of the straddling bucket rank separately against their
// own bases, so perm stays a bijection on each side (con entries con-local).
__global__ __launch_bounds__(256) void csr_fine_kernel(
    const unsigned int* __restrict__ keypay, const int* __restrict__ scanned,
    int* __restrict__ rp, int* __restrict__ esrc, int* __restrict__ perm,
    __half* __restrict__ zvar, __half* __restrict__ zcon,
    int n_nodes, int n_vars, int nbuckets, int total) {
  __shared__ int cnt[BWID];
  __shared__ int pfx[BWID];
  __shared__ int cur[BWID];
  int j = blockIdx.x;
  int t = threadIdx.x;
  if (j == 0 && t < 64) {
    zvar[t] = __float2half(0.0f);
    zcon[t] = __float2half(0.0f);
  }
  int bstart = scanned[(size_t)j * CSB];
  int bend   = scanned[(size_t)(j + 1) * CSB];  // j+1==nbuckets -> scanned[nP]==total
  if (t < BWID) cnt[t] = 0;
  __syncthreads();
  for (int i = bstart + t; i < bend; i += 256)
    atomicAdd(&cnt[keypay[i] >> 25], 1);
  __syncthreads();
  if (t < BWID) pfx[t] = cnt[t];
  __syncthreads();
  for (int off = 1; off < BWID; off <<= 1) {
    int add = (t < BWID && t >= off) ? pfx[t - off] : 0;
    __syncthreads();
    if (t < BWID) pfx[t] += add;
    __syncthreads();
  }
  if (t < BWID) {
    int ex = pfx[t] - cnt[t];  // exclusive prefix within bucket
    cur[t] = ex;
    int node = j * BWID + t;
    if (node < n_nodes) {
      rp[node] = bstart + ex;
      // degree-descending rank within this bucket's var/con subgroup
      bool isv = node < n_vars;
      int mydeg = cnt[t];
      int rank = 0;
      for (int u = 0; u < BWID; ++u) {
        int un = j * BWID + u;
        if (un >= n_nodes) break;            // uniform across threads
        if ((un < n_vars) == isv) {
          int ud = cnt[u];
          if (ud > mydeg || (ud == mydeg && u < t)) ++rank;
        }
      }
      int vbase = j * BWID;
      int cbase = (j * BWID > n_vars) ? (j * BWID) : n_vars;
      perm[(isv ? vbase : cbase) + rank] = isv ? node : (node - n_vars);
    }
  }
  if (j == 0 && t == 0) rp[n_nodes] = total;
  __syncthreads();
  for (int i = bstart + t; i < bend; i += 256) {
    unsigned int kp = keypay[i];
    int off = atomicAdd(&cur[kp >> 25], 1);
    esrc[bstart + off] = (int)(kp & 0x1FFFFFFu);
  }
}

// ---------------- weight pre-conversion (single batched launch) ----------------
// Fragment-major f16 for MFMA B-operands. Converts all four weight sets in
// one dispatch: [0,R*512) v2c | [R*512,2R*512) c2v | +512 ve2 | +512 ce2.
__global__ __launch_bounds__(256) void wcvt_all_kernel(
    const float* __restrict__ Wv2c, h8* __restrict__ Whv2c,
    const float* __restrict__ Wc2v, h8* __restrict__ Whc2v,
    const float* __restrict__ Wve2, h8* __restrict__ Whve2,
    const float* __restrict__ Wce2, h8* __restrict__ Whce2,
    int R512) {
  int tid = blockIdx.x * 256 + threadIdx.x;
  const float* W;
  h8* Wh;
  int local;
  if (tid < R512)                { W = Wv2c; Wh = Whv2c; local = tid; }
  else if (tid < 2 * R512)       { W = Wc2v; Wh = Whc2v; local = tid - R512; }
  else if (tid < 2 * R512 + 512) { W = Wve2; Wh = Whve2; local = tid - 2 * R512; }
  else if (tid < 2 * R512 + 1024){ W = Wce2; Wh = Whce2; local = tid - 2 * R512 - 512; }
  else return;
  int l = local & 63;
  int f = (local >> 6) & 7;
  int r = local >> 9;
  int tt = f >> 1, s = f & 1;
  const float* wp = W + (size_t)r * 4096 + (size_t)(16 * tt + (l & 15)) * 64
                    + 32 * s + 8 * (l >> 4);
  Wh[local] = cvt8(*(const float4*)wp, *(const float4*)(wp + 4));
}

// ---------------- scan ----------------
__global__ __launch_bounds__(256) void scan_blocks_kernel(
    const int* __restrict__ in, int* __restrict__ out,
    int* __restrict__ bsums, int n) {
  __shared__ int s[256];
  int t = threadIdx.x;
  int base = blockIdx.x * SCAN_EPB + t * 4;
  int v[4]; int local = 0;
#pragma unroll
  for (int j = 0; j < 4; ++j) {
    int idx = base + j;
    v[j] = (idx < n) ? in[idx] : 0;
    local += v[j];
  }
  s[t] = local;
  __syncthreads();
  for (int off = 1; off < 256; off <<= 1) {
    int val = (t >= off) ? s[t - off] : 0;
    __syncthreads();
    s[t] += val;
    __syncthreads();
  }
  int run = s[t] - local;
#pragma unroll
  for (int j = 0; j < 4; ++j) {
    int idx = base + j;
    if (idx < n) out[idx] = run;
    run += v[j];
  }
  if (t == 255) bsums[blockIdx.x] = s[255];
}

__global__ __launch_bounds__(256) void scan_sums_kernel(int* __restrict__ bsums, int nb) {
  __shared__ int s[256];
  int t = threadIdx.x;
  int base = t * 4;
  int v[4]; int local = 0;
#pragma unroll
  for (int j = 0; j < 4; ++j) {
    int idx = base + j;
    v[j] = (idx < nb) ? bsums[idx] : 0;
    local += v[j];
  }
  s[t] = local;
  __syncthreads();
  for (int off = 1; off < 256; off <<= 1) {
    int val = (t >= off) ? s[t - off] : 0;
    __syncthreads();
    s[t] += val;
    __syncthreads();
  }
  int run = s[t] - local;
#pragma unroll
  for (int j = 0; j < 4; ++j) {
    int idx = base + j;
    if (idx < nb) bsums[idx] = run;
    run += v[j];
  }
}

__global__ __launch_bounds__(256) void scan_add_kernel(
    int* __restrict__ out, const int* __restrict__ bsums, int n, int total) {
  int t = threadIdx.x;
  int base = blockIdx.x * SCAN_EPB + t * 4;
  int add = bsums[blockIdx.x];
#pragma unroll
  for (int j = 0; j < 4; ++j) {
    int idx = base + j;
    if (idx < n) out[idx] += add;
  }
  if (blockIdx.x == 0 && t == 0) out[n] = total;
}

// ---------------- MFMA fused aggregate + linear + tanh (+ optional readout) ----------------
// 16 degree-ranked dest rows per wave (perm indirection). C/D: col=lane&15,
// row=(lane>>4)*4+reg (m89). R8 gather config = measured best: (256,6)
// spill-free, index prefetch, zero-row unconditional adds. Full grid (one
// batch/wave). perm now comes from csr_fine's free bucket-local ranking.
template<bool RO>
__global__ __launch_bounds__(256, 6) void fused_mfma_kernel(
    __half* __restrict__ hdst, const __half* __restrict__ hsrc,
    const int* __restrict__ rp, const int* __restrict__ esrc,
    const int* __restrict__ perm,
    const h8* __restrict__ Wh, const float* __restrict__ b,
    const float* __restrict__ Wro, const float* __restrict__ bro,
    float* __restrict__ scores, int n_rows, int zrow) {
  int t = threadIdx.x;
  int wave = t >> 6, lane = t & 63;
  int mm = lane & 15;   // dest-row slot within the 16-row batch
  int fb = lane >> 4;   // feature-block 0..3

  float brov = RO ? bro[0] : 0.0f;

  const float4* rows4 = (const float4*)hsrc;  // 8 float4 per 64-half row

  int stride16 = gridDim.x * WPB * 16;
  for (int rowb = (blockIdx.x * WPB + wave) * 16; rowb < n_rows; rowb += stride16) {
    int lrow = rowb + mm;                      // logical (degree-ranked) row
    int lc = (lrow < n_rows) ? lrow : n_rows - 1;
    int mc = perm[lc];                         // actual dest row
    int p = rp[mc], end = rp[mc + 1];
    float degf = (float)(end - p);

    h8 a0 = h8zero(), a1 = h8zero();

    // prologue: indices for the first 4-edge batch
    int s0, s1, s2, s3;
    {
      bool v0 = p < end, v1 = p + 1 < end, v2 = p + 2 < end, v3 = p + 3 < end;
      s0 = esrc[v0 ? p : 0];     s0 = v0 ? s0 : zrow;
      s1 = esrc[v1 ? p + 1 : 0]; s1 = v1 ? s1 : zrow;
      s2 = esrc[v2 ? p + 2 : 0]; s2 = v2 ? s2 : zrow;
      s3 = esrc[v3 ? p + 3 : 0]; s3 = v3 ? s3 : zrow;
    }

    while (__any(p < end)) {
      // issue row loads for the CURRENT indices (latency-bound work)
      float4 q0a = rows4[(size_t)s0 * 8 + fb];
      float4 q0b = rows4[(size_t)s0 * 8 + 4 + fb];
      float4 q1a = rows4[(size_t)s1 * 8 + fb];
      float4 q1b = rows4[(size_t)s1 * 8 + 4 + fb];
      float4 q2a = rows4[(size_t)s2 * 8 + fb];
      float4 q2b = rows4[(size_t)s2 * 8 + 4 + fb];
      float4 q3a = rows4[(size_t)s3 * 8 + fb];
      float4 q3b = rows4[(size_t)s3 * 8 + 4 + fb];

      // prefetch NEXT batch's indices while rows are in flight
      int np = p + 4;
      {
        bool w0 = np < end, w1 = np + 1 < end, w2 = np + 2 < end, w3 = np + 3 < end;
        int u0 = esrc[w0 ? np : 0];     s0 = w0 ? u0 : zrow;
        int u1 = esrc[w1 ? np + 1 : 0]; s1 = w1 ? u1 : zrow;
        int u2 = esrc[w2 ? np + 2 : 0]; s2 = w2 ? u2 : zrow;
        int u3 = esrc[w3 ? np + 3 : 0]; s3 = w3 ? u3 : zrow;
      }

      // accumulate (unconditional: tail batches gathered the zero row)
      a0 += __builtin_bit_cast(h8, q0a);
      a1 += __builtin_bit_cast(h8, q0b);
      a0 += __builtin_bit_cast(h8, q1a);
      a1 += __builtin_bit_cast(h8, q1b);
      a0 += __builtin_bit_cast(h8, q2a);
      a1 += __builtin_bit_cast(h8, q2b);
      a0 += __builtin_bit_cast(h8, q3a);
      a1 += __builtin_bit_cast(h8, q3b);
      p = np;
    }

    // Loop-variant opaque offset: keeps the B-fragment / bias loads from
    // being hoisted (LICM) into a live range spanning the gather loop.
    int zoff = 0;
    asm volatile("" : "+v"(zoff));
    const h8* Whb = Wh + zoff;
    const float* bb = b + zoff;
    const float* wrob = RO ? (Wro + zoff) : nullptr;

    float pr[4] = {0.f, 0.f, 0.f, 0.f};
#pragma unroll
    for (int h = 0; h < 2; ++h) {
      __builtin_amdgcn_sched_barrier(0);
      h8 Bf[2][2];
      float bvt[2], wrot[2];
#pragma unroll
      for (int s = 0; s < 2; ++s) {
        int tt = 2 * h + s;
#pragma unroll
        for (int ks = 0; ks < 2; ++ks)
          Bf[s][ks] = Whb[(tt * 2 + ks) * 64 + lane];
        bvt[s] = bb[16 * tt + mm];
        wrot[s] = RO ? wrob[16 * tt + mm] : 0.0f;
      }

      f32x4 d[2];
#pragma unroll
      for (int s = 0; s < 2; ++s) {
        f32x4 dz; dz[0] = 0.f; dz[1] = 0.f; dz[2] = 0.f; dz[3] = 0.f;
        d[s] = __builtin_amdgcn_mfma_f32_16x16x32_f16(a0, Bf[s][0], dz, 0, 0, 0);
        d[s] = __builtin_amdgcn_mfma_f32_16x16x32_f16(a1, Bf[s][1], d[s], 0, 0, 0);
      }

      // epilogue: lane l, reg i, tile tt -> logical row rowb+4fb+i -> actual
      // row via shuffle of mc from lane (4fb+i); col 16tt + mm.
#pragma unroll
      for (int i = 0; i < 4; ++i) {
        float deg_i = __shfl(degf, fb * 4 + i, 64);
        int arow = __shfl(mc, fb * 4 + i, 64);
        bool ok = (rowb + fb * 4 + i) < n_rows;
#pragma unroll
        for (int s = 0; s < 2; ++s) {
          int tt = 2 * h + s;
          size_t addr = (size_t)arow * 64 + 16 * tt + mm;
          float hold = ok ? __half2float(hdst[addr]) : 0.0f;
          float hv = tanhf(hold + bvt[s] * deg_i + d[s][i]);
          if (RO) {
            pr[i] += hv * wrot[s];
          } else {
            if (ok) hdst[addr] = __float2half(hv);
          }
        }
      }
    }

    if (RO) {
#pragma unroll
      for (int i = 0; i < 4; ++i) {
        float pv = pr[i];
        pv += __shfl_xor(pv, 1, 64);
        pv += __shfl_xor(pv, 2, 64);
        pv += __shfl_xor(pv, 4, 64);
        pv += __shfl_xor(pv, 8, 64);
        int arow = __shfl(mc, fb * 4 + i, 64);
        bool ok = (rowb + fb * 4 + i) < n_rows;
        if (mm == 0 && ok) scores[arow] = pv + brov;
      }
    }
  }
}

// Encoders keep the CAPPED persistent grid (W->VGPR preamble replicates per
// block); fused kernels use the FULL grid (tiny preamble, finer granularity).
static inline int rowgrid16cap(int n) {
  int want = (n + WPB * 16 - 1) / (WPB * 16);
  return want < 2048 ? want : 2048;
}
static inline int rowgrid16full(int n) {
  return (n + WPB * 16 - 1) / (WPB * 16);
}

extern "C" void kernel_launch(void* const* d_in, const int* in_sizes, int n_in,
                              void* d_out, int out_size, void* d_ws, size_t ws_size,
                              hipStream_t stream) {
  const float* vf    = (const float*)d_in[0];
  const float* cf    = (const float*)d_in[1];
  const int*   ev    = (const int*)d_in[2];
  const int*   ec    = (const int*)d_in[3];
  const float* W_ve1 = (const float*)d_in[4];
  const float* b_ve1 = (const float*)d_in[5];
  const float* W_ve2 = (const float*)d_in[6];
  const float* b_ve2 = (const float*)d_in[7];
  const float* W_ce1 = (const float*)d_in[8];
  const float* b_ce1 = (const float*)d_in[9];
  const float* W_ce2 = (const float*)d_in[10];
  const float* b_ce2 = (const float*)d_in[11];
  const float* W_v2c = (const float*)d_in[12];
  const float* b_v2c = (const float*)d_in[13];
  const float* W_c2v = (const float*)d_in[14];
  const float* b_c2v = (const float*)d_in[15];
  const float* W_ro  = (const float*)d_in[16];
  const float* b_ro  = (const float*)d_in[17];

  const int n_vars  = in_sizes[0] / 7;
  const int n_cons  = in_sizes[1] / 5;
  const int n_edges = in_sizes[2];
  const int R       = in_sizes[12] / (64 * 64);
  const int n_nodes = n_vars + n_cons;

  // Persistent workspace (~50.5 MB of a ~55 MB budget). Each h table gets
  // ONE extra all-zero row (index n_rows) for the tail-edge gather.
  char* p = (char*)d_ws;
  __half* h_var = (__half*)p; p += ((size_t)n_vars + 1) * 64 * 2;  // 25.6 MB
  __half* h_con = (__half*)p; p += ((size_t)n_cons + 1) * 64 * 2;  // 12.8 MB
  int*   rp     = (int*)p;   p += (size_t)(n_nodes + 1) * 4;  // merged [vars|cons]
  int*   esrc   = (int*)p;   p += (size_t)2 * n_edges * 4;    // v-slots [0,E), c-slots [E,2E)
  int*   bsums  = (int*)p;   p += 1024 * 4;
  h8*    wh_v2c = (h8*)p;    p += (size_t)R * 512 * 16;       // frag-major f16
  h8*    wh_c2v = (h8*)p;    p += (size_t)R * 512 * 16;
  h8*    wh_ve2 = (h8*)p;    p += (size_t)512 * 16;           // encoder W2 frags
  h8*    wh_ce2 = (h8*)p;    p += (size_t)512 * 16;
  int*   perm   = (int*)p;   p += (size_t)n_nodes * 4;        // degree-ranked rows (1.2 MB)

  // Build-phase scratch ALIASES the feature buffers (encoders run only after
  // csr_fine_kernel, the last reader of this scratch):
  //   edge-sort partial+scanned (~7.2 MB) live in h_var (25.6 MB)
  //   keypay (2E uints = 9.6 MB) lives in h_con (12.8 MB)
  // Zero rows sit at the END of each h table -- outside the scratch.
  const int nbuckets = (n_nodes + BWID - 1) >> BSH;           // 2344 @ 300k nodes
  const int nP = nbuckets * CSB;                              // 900,096 < 1M scan cap
  int* partial = (int*)h_var;
  int* scanned = partial + (size_t)(nP + 1);
  unsigned int* keypay = (unsigned int*)h_con;

  const int nb2 = (nP + SCAN_EPB - 1) / SCAN_EPB;             // 879 <= 1024

  // --- CSR build: coarse hist -> scan -> coarse place -> fine sub-CSR(+perm) ---
  bucket_hist_kernel<<<CSB, 256, nbuckets * 4, stream>>>(
      ev, ec, partial, n_edges, n_vars, nbuckets);

  // weight pre-conversion: all four sets, ONE launch
  {
    int total = 2 * R * 512 + 1024;
    wcvt_all_kernel<<<(total + 255) / 256, 256, 0, stream>>>(
        W_v2c, wh_v2c, W_c2v, wh_c2v, W_ve2, wh_ve2, W_ce2, wh_ce2, R * 512);
  }

  scan_blocks_kernel<<<nb2, 256, 0, stream>>>(partial, scanned, bsums, nP);
  scan_sums_kernel<<<1, 256, 0, stream>>>(bsums, nb2);
  scan_add_kernel<<<nb2, 256, 0, stream>>>(scanned, bsums, nP, 2 * n_edges);

  bucket_place_kernel<<<CSB, 256, nbuckets * 4, stream>>>(
      ev, ec, scanned, keypay, n_edges, n_vars, nbuckets);
  csr_fine_kernel<<<nbuckets, 256, 0, stream>>>(
      keypay, scanned, rp, esrc, perm,
      h_var + (size_t)n_vars * 64, h_con + (size_t)n_cons * 64,
      n_nodes, n_vars, nbuckets, 2 * n_edges);

  // encoders AFTER the build (their outputs host the build scratch)
  encoder_mfma_kernel<7><<<rowgrid16cap(n_vars), 256, 0, stream>>>(
      vf, W_ve1, b_ve1, wh_ve2, b_ve2, h_var, n_vars);
  encoder_mfma_kernel<5><<<rowgrid16cap(n_cons), 256, 0, stream>>>(
      cf, W_ce1, b_ce1, wh_ce2, b_ce2, h_con, n_cons);

  for (int r = 0; r < R; ++r) {
    fused_mfma_kernel<false><<<rowgrid16full(n_cons), 256, 0, stream>>>(
        h_con, h_var, rp + n_vars, esrc, perm + n_vars,
        wh_v2c + (size_t)r * 512, b_v2c + (size_t)r * 64,
        nullptr, nullptr, nullptr, n_cons, n_vars);
    if (r == R - 1) {
      fused_mfma_kernel<true><<<rowgrid16full(n_vars), 256, 0, stream>>>(
          h_var, h_con, rp, esrc, perm,
          wh_c2v + (size_t)r * 512, b_c2v + (size_t)r * 64,
          W_ro, b_ro, (float*)d_out, n_vars, n_cons);
    } else {
      fused_mfma_kernel<false><<<rowgrid16full(n_vars), 256, 0, stream>>>(
          h_var, h_con, rp, esrc, perm,
          wh_c2v + (size_t)r * 512, b_c2v + (size_t)r * 64,
          nullptr, nullptr, nullptr, n_vars, n_cons);
    }
  }
}

// Round 14
// 367.879 us; speedup vs baseline: 1.0616x; 1.0616x over previous
//
#include <hip/hip_runtime.h>
#include <hip/hip_bf16.h>
#include <hip/hip_fp16.h>

#define WPB 4          // waves per block (256 threads)
#define SCAN_EPB 1024  // elements per scan block (256 thr x 4)

// counting-sort CSR build (replaces scattered-atomic hist+rank+place):
#define CSB 384        // blocks in coarse hist/place passes (nP = CSB*nbuckets must stay < 1M for scan chain)
#define BSH 7          // bucket shift: 128 nodes per coarse bucket
#define BWID 128       // 1 << BSH

typedef _Float16 h8 __attribute__((ext_vector_type(8)));
typedef float f32x4 __attribute__((ext_vector_type(4)));

__device__ __forceinline__ float bcast(float v, int i) {
  return __builtin_bit_cast(float, __builtin_amdgcn_readlane(__builtin_bit_cast(int, v), i));
}
__device__ __forceinline__ h8 h8zero() {
  h8 r;
#pragma unroll
  for (int j = 0; j < 8; ++j) r[j] = (_Float16)0;
  return r;
}
__device__ __forceinline__ h8 cvt8(float4 a, float4 b) {
  h8 r;
  r[0] = (_Float16)a.x; r[1] = (_Float16)a.y; r[2] = (_Float16)a.z; r[3] = (_Float16)a.w;
  r[4] = (_Float16)b.x; r[5] = (_Float16)b.y; r[6] = (_Float16)b.z; r[7] = (_Float16)b.w;
  return r;
}

// ---------------- encoders (MFMA layer 2) ----------------
// out = tanh(x @ W1^T + b1) @ W2^T + b2.
// Layer 1: f32 scalar, lane = hidden feature. Layer 2: 8x mfma_16x16x32_f16
// per 16-row group against pre-converted W2 fragments; b2 folded into C-init.
// Hidden goes through a per-wave XOR-swizzled LDS transpose (chunk ^= row&7
// keeps writes and b128 reads <=2-way bank aliasing = free, m136).
template<int IN_F>
__global__ __launch_bounds__(256, 4) void encoder_mfma_kernel(
    const float* __restrict__ x,
    const float* __restrict__ W1, const float* __restrict__ b1,
    const h8* __restrict__ W2h, const float* __restrict__ b2,
    __half* __restrict__ out, int n_rows) {
  __shared__ _Float16 hlds[WPB][16][64];
  int t = threadIdx.x;
  int wave = t >> 6, lane = t & 63;
  int mm = lane & 15, fb = lane >> 4;

  float w1reg[IN_F];
#pragma unroll
  for (int j = 0; j < IN_F; ++j) w1reg[j] = W1[lane * IN_F + j];
  float b1v = b1[lane];

  h8 Bf[4][2];
  float bvt[4];
#pragma unroll
  for (int tt = 0; tt < 4; ++tt) {
#pragma unroll
    for (int s = 0; s < 2; ++s) Bf[tt][s] = W2h[(tt * 2 + s) * 64 + lane];
    bvt[tt] = b2[16 * tt + mm];
  }

  // swizzled 16B-chunk offsets for the A-fragment reads (row = mm)
  int c0 = ((fb ^ (mm & 7)) << 3);        // logical k in [8fb, 8fb+8)
  int c1 = (((4 + fb) ^ (mm & 7)) << 3);  // logical k in [32+8fb, 32+8fb+8)

  const int ntot = n_rows * IN_F;
  int stride16 = gridDim.x * WPB * 16;
  for (int rowb = (blockIdx.x * WPB + wave) * 16; rowb < n_rows; rowb += stride16) {
    int base = rowb * IN_F;
    float xa = 0.0f, xb = 0.0f;
    if (base + lane < ntot) xa = x[base + lane];
    if (base + 64 + lane < ntot) xb = x[base + 64 + lane];

#pragma unroll
    for (int r = 0; r < 16; ++r) {
      float h = b1v;
#pragma unroll
      for (int j = 0; j < IN_F; ++j) {
        int idx = r * IN_F + j;  // compile-time after unroll
        float xv;
        if (idx < 64) xv = bcast(xa, idx); else xv = bcast(xb, idx - 64);
        h += w1reg[j] * xv;
      }
      int sc = ((((lane >> 3) ^ (r & 7)) << 3) | (lane & 7));
      hlds[wave][r][sc] = (_Float16)tanhf(h);
    }

    // per-wave LDS slice: within-wave ds_write->ds_read ordering is handled
    // by compiler-inserted lgkmcnt; no barrier needed.
    h8 a0 = *(const h8*)&hlds[wave][mm][c0];
    h8 a1 = *(const h8*)&hlds[wave][mm][c1];

    f32x4 d[4];
#pragma unroll
    for (int tt = 0; tt < 4; ++tt) {
      f32x4 dz; dz[0] = bvt[tt]; dz[1] = bvt[tt]; dz[2] = bvt[tt]; dz[3] = bvt[tt];
      d[tt] = __builtin_amdgcn_mfma_f32_16x16x32_f16(a0, Bf[tt][0], dz, 0, 0, 0);
      d[tt] = __builtin_amdgcn_mfma_f32_16x16x32_f16(a1, Bf[tt][1], d[tt], 0, 0, 0);
    }

    // D: col = lane&15 (mm), row = fb*4 + reg (m89)
#pragma unroll
    for (int i = 0; i < 4; ++i) {
      int grow = rowb + fb * 4 + i;
      if (grow < n_rows) {
#pragma unroll
        for (int tt = 0; tt < 4; ++tt)
          out[(size_t)grow * 64 + 16 * tt + mm] = __float2half(d[tt][i]);
      }
    }
  }
}

// ---------------- CSR build: two-level counting sort, NO global atomics ----------------
// The 2.4M scattered global atomics of the old hist_rank pass ran at the
// ~22-26 G atomics/s transaction floor (106 us, 84 MB write-through traffic).
// Counting sort by dest does the same job with LDS atomics + streaming I/O.
// Rank order within a dest is arbitrary (was atomic-order before), so any
// entry->slot bijection is valid.

__global__ __launch_bounds__(256) void bucket_hist_kernel(
    const int* __restrict__ ev, const int* __restrict__ ec,
    int* __restrict__ partial, int n_edges, int n_vars, int nbuckets) {
  extern __shared__ int cnt[];
  int t = threadIdx.x;
  for (int i = t; i < nbuckets; i += 256) cnt[i] = 0;
  __syncthreads();
  int chunk = (n_edges + CSB - 1) / CSB;
  int lo = blockIdx.x * chunk;
  int hi = lo + chunk; if (hi > n_edges) hi = n_edges;
  for (int e = lo + t; e < hi; e += 256) {
    int v = ev[e], c = ec[e];
    atomicAdd(&cnt[v >> BSH], 1);
    atomicAdd(&cnt[(n_vars + c) >> BSH], 1);
  }
  __syncthreads();
  // bucket-major layout so one exclusive scan yields global slot bases
  for (int i = t; i < nbuckets; i += 256)
    partial[(size_t)i * CSB + blockIdx.x] = cnt[i];
}

// Coarse place: LDS cursors start at this block's scanned bases; entries are
// written grouped by coarse bucket. keypay packs (key & 127)<<25 | payload
// (payload < 2^25: node ids <= 200k).
__global__ __launch_bounds__(256) void bucket_place_kernel(
    const int* __restrict__ ev, const int* __restrict__ ec,
    const int* __restrict__ scanned, unsigned int* __restrict__ keypay,
    int n_edges, int n_vars, int nbuckets) {
  extern __shared__ int cur[];
  int t = threadIdx.x;
  for (int i = t; i < nbuckets; i += 256)
    cur[i] = scanned[(size_t)i * CSB + blockIdx.x];
  __syncthreads();
  int chunk = (n_edges + CSB - 1) / CSB;  // MUST match bucket_hist_kernel
  int lo = blockIdx.x * chunk;
  int hi = lo + chunk; if (hi > n_edges) hi = n_edges;
  for (int e = lo + t; e < hi; e += 256) {
    int v = ev[e], c = ec[e];
    int mc = n_vars + c;
    int s1 = atomicAdd(&cur[v >> BSH], 1);
    keypay[s1] = ((unsigned)(v & (BWID - 1)) << 25) | (unsigned)c;
    int s2 = atomicAdd(&cur[mc >> BSH], 1);
    keypay[s2] = ((unsigned)(mc & (BWID - 1)) << 25) | (unsigned)v;
  }
}

// Fine pass: one block per coarse bucket (contiguous segment of keypay).
// Builds the exact 128-node sub-CSR in LDS, emits rp + esrc coalesced.
// Block 0 also zero-fills the two 128-B tail rows (zrow) of h_var/h_con
// (outside the aliased scratch; replaces two hipMemsetAsync launches).
__global__ __launch_bounds__(256) void csr_fine_kernel(
    const unsigned int* __restrict__ keypay, const int* __restrict__ scanned,
    int* __restrict__ rp, int* __restrict__ esrc,
    __half* __restrict__ zvar, __half* __restrict__ zcon,
    int n_nodes, int nbuckets, int total) {
  __shared__ int cnt[BWID];
  __shared__ int pfx[BWID];
  __shared__ int cur[BWID];
  int j = blockIdx.x;
  int t = threadIdx.x;
  if (j == 0 && t < 64) {
    zvar[t] = __float2half(0.0f);
    zcon[t] = __float2half(0.0f);
  }
  int bstart = scanned[(size_t)j * CSB];
  int bend   = scanned[(size_t)(j + 1) * CSB];  // j+1==nbuckets -> scanned[nP]==total
  if (t < BWID) cnt[t] = 0;
  __syncthreads();
  for (int i = bstart + t; i < bend; i += 256)
    atomicAdd(&cnt[keypay[i] >> 25], 1);
  __syncthreads();
  if (t < BWID) pfx[t] = cnt[t];
  __syncthreads();
  for (int off = 1; off < BWID; off <<= 1) {
    int add = (t < BWID && t >= off) ? pfx[t - off] : 0;
    __syncthreads();
    if (t < BWID) pfx[t] += add;
    __syncthreads();
  }
  if (t < BWID) {
    int ex = pfx[t] - cnt[t];  // exclusive prefix within bucket
    cur[t] = ex;
    int node = j * BWID + t;
    if (node < n_nodes) rp[node] = bstart + ex;
  }
  if (j == 0 && t == 0) rp[n_nodes] = total;
  __syncthreads();
  for (int i = bstart + t; i < bend; i += 256) {
    unsigned int kp = keypay[i];
    int off = atomicAdd(&cur[kp >> 25], 1);
    esrc[bstart + off] = (int)(kp & 0x1FFFFFFu);
  }
}

// ---------------- weight pre-conversion (single batched launch) ----------------
// Fragment-major f16 for MFMA B-operands. Converts all four weight sets in
// one dispatch: [0,R*512) v2c | [R*512,2R*512) c2v | +512 ve2 | +512 ce2.
__global__ __launch_bounds__(256) void wcvt_all_kernel(
    const float* __restrict__ Wv2c, h8* __restrict__ Whv2c,
    const float* __restrict__ Wc2v, h8* __restrict__ Whc2v,
    const float* __restrict__ Wve2, h8* __restrict__ Whve2,
    const float* __restrict__ Wce2, h8* __restrict__ Whce2,
    int R512) {
  int tid = blockIdx.x * 256 + threadIdx.x;
  const float* W;
  h8* Wh;
  int local;
  if (tid < R512)                { W = Wv2c; Wh = Whv2c; local = tid; }
  else if (tid < 2 * R512)       { W = Wc2v; Wh = Whc2v; local = tid - R512; }
  else if (tid < 2 * R512 + 512) { W = Wve2; Wh = Whve2; local = tid - 2 * R512; }
  else if (tid < 2 * R512 + 1024){ W = Wce2; Wh = Whce2; local = tid - 2 * R512 - 512; }
  else return;
  int l = local & 63;
  int f = (local >> 6) & 7;
  int r = local >> 9;
  int tt = f >> 1, s = f & 1;
  const float* wp = W + (size_t)r * 4096 + (size_t)(16 * tt + (l & 15)) * 64
                    + 32 * s + 8 * (l >> 4);
  Wh[local] = cvt8(*(const float4*)wp, *(const float4*)(wp + 4));
}

// ---------------- scan (reused for the CSB x nbuckets partial array) ----------------
__global__ __launch_bounds__(256) void scan_blocks_kernel(
    const int* __restrict__ in, int* __restrict__ out,
    int* __restrict__ bsums, int n) {
  __shared__ int s[256];
  int t = threadIdx.x;
  int base = blockIdx.x * SCAN_EPB + t * 4;
  int v[4]; int local = 0;
#pragma unroll
  for (int j = 0; j < 4; ++j) {
    int idx = base + j;
    v[j] = (idx < n) ? in[idx] : 0;
    local += v[j];
  }
  s[t] = local;
  __syncthreads();
  for (int off = 1; off < 256; off <<= 1) {
    int val = (t >= off) ? s[t - off] : 0;
    __syncthreads();
    s[t] += val;
    __syncthreads();
  }
  int run = s[t] - local;
#pragma unroll
  for (int j = 0; j < 4; ++j) {
    int idx = base + j;
    if (idx < n) out[idx] = run;
    run += v[j];
  }
  if (t == 255) bsums[blockIdx.x] = s[255];
}

__global__ __launch_bounds__(256) void scan_sums_kernel(int* __restrict__ bsums, int nb) {
  __shared__ int s[256];
  int t = threadIdx.x;
  int base = t * 4;
  int v[4]; int local = 0;
#pragma unroll
  for (int j = 0; j < 4; ++j) {
    int idx = base + j;
    v[j] = (idx < nb) ? bsums[idx] : 0;
    local += v[j];
  }
  s[t] = local;
  __syncthreads();
  for (int off = 1; off < 256; off <<= 1) {
    int val = (t >= off) ? s[t - off] : 0;
    __syncthreads();
    s[t] += val;
    __syncthreads();
  }
  int run = s[t] - local;
#pragma unroll
  for (int j = 0; j < 4; ++j) {
    int idx = base + j;
    if (idx < nb) bsums[idx] = run;
    run += v[j];
  }
}

__global__ __launch_bounds__(256) void scan_add_kernel(
    int* __restrict__ out, const int* __restrict__ bsums, int n, int total) {
  int t = threadIdx.x;
  int base = blockIdx.x * SCAN_EPB + t * 4;
  int add = bsums[blockIdx.x];
#pragma unroll
  for (int j = 0; j < 4; ++j) {
    int idx = base + j;
    if (idx < n) out[idx] += add;
  }
  if (blockIdx.x == 0 && t == 0) out[n] = total;
}

// ---------------- MFMA fused aggregate + linear + tanh (+ optional readout) ----------------
// 16 consecutive dest rows per wave. C/D: col=lane&15, row=(lane>>4)*4+reg (m89).
// R8 configuration = measured best. R9 (deeper row dbuf @ (256,5)) regressed;
// R11-R13 (degree perms: global asc/desc, bucket-local) all netted >= R10's
// total. Little's-law check: ~76 MB of L3-served random 128-B rows at ~550 cy
// needs ~350 KB outstanding; 256 CU x ~12 waves x 8 x 16 B ~= 390 KB -- the
// gather runs AT the concurrency ceiling the register budget permits.
template<bool RO>
__global__ __launch_bounds__(256, 6) void fused_mfma_kernel(
    __half* __restrict__ hdst, const __half* __restrict__ hsrc,
    const int* __restrict__ rp, const int* __restrict__ esrc,
    const h8* __restrict__ Wh, const float* __restrict__ b,
    const float* __restrict__ Wro, const float* __restrict__ bro,
    float* __restrict__ scores, int n_rows, int zrow) {
  int t = threadIdx.x;
  int wave = t >> 6, lane = t & 63;
  int mm = lane & 15;   // dest-row slot within the 16-row batch
  int fb = lane >> 4;   // feature-block 0..3

  float brov = RO ? bro[0] : 0.0f;

  const float4* rows4 = (const float4*)hsrc;  // 8 float4 per 64-half row

  int stride16 = gridDim.x * WPB * 16;
  for (int rowb = (blockIdx.x * WPB + wave) * 16; rowb < n_rows; rowb += stride16) {
    int mrow = rowb + mm;
    int mc = (mrow < n_rows) ? mrow : n_rows - 1;
    int p = rp[mc], end = rp[mc + 1];
    float degf = (float)(end - p);

    h8 a0 = h8zero(), a1 = h8zero();

    // prologue: indices for the first 4-edge batch
    int s0, s1, s2, s3;
    {
      bool v0 = p < end, v1 = p + 1 < end, v2 = p + 2 < end, v3 = p + 3 < end;
      s0 = esrc[v0 ? p : 0];     s0 = v0 ? s0 : zrow;
      s1 = esrc[v1 ? p + 1 : 0]; s1 = v1 ? s1 : zrow;
      s2 = esrc[v2 ? p + 2 : 0]; s2 = v2 ? s2 : zrow;
      s3 = esrc[v3 ? p + 3 : 0]; s3 = v3 ? s3 : zrow;
    }

    while (__any(p < end)) {
      // issue row loads for the CURRENT indices (latency-bound work)
      float4 q0a = rows4[(size_t)s0 * 8 + fb];
      float4 q0b = rows4[(size_t)s0 * 8 + 4 + fb];
      float4 q1a = rows4[(size_t)s1 * 8 + fb];
      float4 q1b = rows4[(size_t)s1 * 8 + 4 + fb];
      float4 q2a = rows4[(size_t)s2 * 8 + fb];
      float4 q2b = rows4[(size_t)s2 * 8 + 4 + fb];
      float4 q3a = rows4[(size_t)s3 * 8 + fb];
      float4 q3b = rows4[(size_t)s3 * 8 + 4 + fb];

      // prefetch NEXT batch's indices while rows are in flight
      int np = p + 4;
      {
        bool w0 = np < end, w1 = np + 1 < end, w2 = np + 2 < end, w3 = np + 3 < end;
        int u0 = esrc[w0 ? np : 0];     s0 = w0 ? u0 : zrow;
        int u1 = esrc[w1 ? np + 1 : 0]; s1 = w1 ? u1 : zrow;
        int u2 = esrc[w2 ? np + 2 : 0]; s2 = w2 ? u2 : zrow;
        int u3 = esrc[w3 ? np + 3 : 0]; s3 = w3 ? u3 : zrow;
      }

      // accumulate (unconditional: tail batches gathered the zero row)
      a0 += __builtin_bit_cast(h8, q0a);
      a1 += __builtin_bit_cast(h8, q0b);
      a0 += __builtin_bit_cast(h8, q1a);
      a1 += __builtin_bit_cast(h8, q1b);
      a0 += __builtin_bit_cast(h8, q2a);
      a1 += __builtin_bit_cast(h8, q2b);
      a0 += __builtin_bit_cast(h8, q3a);
      a1 += __builtin_bit_cast(h8, q3b);
      p = np;
    }

    // Loop-variant opaque offset: keeps the B-fragment / bias loads from
    // being hoisted (LICM) into a live range spanning the gather loop.
    int zoff = 0;
    asm volatile("" : "+v"(zoff));
    const h8* Whb = Wh + zoff;
    const float* bb = b + zoff;
    const float* wrob = RO ? (Wro + zoff) : nullptr;

    float pr[4] = {0.f, 0.f, 0.f, 0.f};
#pragma unroll
    for (int h = 0; h < 2; ++h) {
      __builtin_amdgcn_sched_barrier(0);
      h8 Bf[2][2];
      float bvt[2], wrot[2];
#pragma unroll
      for (int s = 0; s < 2; ++s) {
        int tt = 2 * h + s;
#pragma unroll
        for (int ks = 0; ks < 2; ++ks)
          Bf[s][ks] = Whb[(tt * 2 + ks) * 64 + lane];
        bvt[s] = bb[16 * tt + mm];
        wrot[s] = RO ? wrob[16 * tt + mm] : 0.0f;
      }

      f32x4 d[2];
#pragma unroll
      for (int s = 0; s < 2; ++s) {
        f32x4 dz; dz[0] = 0.f; dz[1] = 0.f; dz[2] = 0.f; dz[3] = 0.f;
        d[s] = __builtin_amdgcn_mfma_f32_16x16x32_f16(a0, Bf[s][0], dz, 0, 0, 0);
        d[s] = __builtin_amdgcn_mfma_f32_16x16x32_f16(a1, Bf[s][1], d[s], 0, 0, 0);
      }

      // epilogue: lane l, reg i, tile tt -> row rowb + 4*fb + i, col 16tt + mm
#pragma unroll
      for (int i = 0; i < 4; ++i) {
        float deg_i = __shfl(degf, fb * 4 + i, 64);
        int grow = rowb + fb * 4 + i;
        bool ok = grow < n_rows;
#pragma unroll
        for (int s = 0; s < 2; ++s) {
          int tt = 2 * h + s;
          size_t addr = (size_t)grow * 64 + 16 * tt + mm;
          float hold = ok ? __half2float(hdst[addr]) : 0.0f;
          float hv = tanhf(hold + bvt[s] * deg_i + d[s][i]);
          if (RO) {
            pr[i] += hv * wrot[s];
          } else {
            if (ok) hdst[addr] = __float2half(hv);
          }
        }
      }
    }

    if (RO) {
#pragma unroll
      for (int i = 0; i < 4; ++i) {
        float pv = pr[i];
        pv += __shfl_xor(pv, 1, 64);
        pv += __shfl_xor(pv, 2, 64);
        pv += __shfl_xor(pv, 4, 64);
        pv += __shfl_xor(pv, 8, 64);
        int grow = rowb + fb * 4 + i;
        if (mm == 0 && grow < n_rows) scores[grow] = pv + brov;
      }
    }
  }
}

// Capped persistent grids (R9: full grids replicate preambles, 2.3x regression).
static inline int rowgrid16(int n) {
  int want = (n + WPB * 16 - 1) / (WPB * 16);
  return want < 2048 ? want : 2048;
}

extern "C" void kernel_launch(void* const* d_in, const int* in_sizes, int n_in,
                              void* d_out, int out_size, void* d_ws, size_t ws_size,
                              hipStream_t stream) {
  const float* vf    = (const float*)d_in[0];
  const float* cf    = (const float*)d_in[1];
  const int*   ev    = (const int*)d_in[2];
  const int*   ec    = (const int*)d_in[3];
  const float* W_ve1 = (const float*)d_in[4];
  const float* b_ve1 = (const float*)d_in[5];
  const float* W_ve2 = (const float*)d_in[6];
  const float* b_ve2 = (const float*)d_in[7];
  const float* W_ce1 = (const float*)d_in[8];
  const float* b_ce1 = (const float*)d_in[9];
  const float* W_ce2 = (const float*)d_in[10];
  const float* b_ce2 = (const float*)d_in[11];
  const float* W_v2c = (const float*)d_in[12];
  const float* b_v2c = (const float*)d_in[13];
  const float* W_c2v = (const float*)d_in[14];
  const float* b_c2v = (const float*)d_in[15];
  const float* W_ro  = (const float*)d_in[16];
  const float* b_ro  = (const float*)d_in[17];

  const int n_vars  = in_sizes[0] / 7;
  const int n_cons  = in_sizes[1] / 5;
  const int n_edges = in_sizes[2];
  const int R       = in_sizes[12] / (64 * 64);
  const int n_nodes = n_vars + n_cons;

  // Persistent workspace (~49.3 MB of a ~55 MB budget). Each h table gets
  // ONE extra all-zero row (index n_rows) for the tail-edge gather.
  char* p = (char*)d_ws;
  __half* h_var = (__half*)p; p += ((size_t)n_vars + 1) * 64 * 2;  // 25.6 MB
  __half* h_con = (__half*)p; p += ((size_t)n_cons + 1) * 64 * 2;  // 12.8 MB
  int*   rp     = (int*)p;   p += (size_t)(n_nodes + 1) * 4;  // merged [vars|cons]
  int*   esrc   = (int*)p;   p += (size_t)2 * n_edges * 4;    // v-slots [0,E), c-slots [E,2E)
  int*   bsums  = (int*)p;   p += 1024 * 4;
  h8*    wh_v2c = (h8*)p;    p += (size_t)R * 512 * 16;       // frag-major f16
  h8*    wh_c2v = (h8*)p;    p += (size_t)R * 512 * 16;
  h8*    wh_ve2 = (h8*)p;    p += (size_t)512 * 16;           // encoder W2 frags
  h8*    wh_ce2 = (h8*)p;    p += (size_t)512 * 16;

  // Build-phase scratch ALIASES the feature buffers (encoders run only after
  // csr_fine_kernel, the last reader of this scratch):
  //   partial + scanned (2 x (nP+1) ints ~= 7.2 MB) live in h_var (25.6 MB)
  //   keypay (2E uints = 9.6 MB) lives in h_con (12.8 MB)
  // Zero rows sit at the END of each h table -- outside the scratch.
  const int nbuckets = (n_nodes + BWID - 1) >> BSH;           // 2344 @ 300k nodes
  const int nP = nbuckets * CSB;                              // 900,096 < 1M scan cap
  int* partial = (int*)h_var;
  int* scanned = partial + (size_t)(nP + 1);
  unsigned int* keypay = (unsigned int*)h_con;

  const int nb2 = (nP + SCAN_EPB - 1) / SCAN_EPB;             // 879 <= 1024

  // --- CSR build: coarse hist -> scan -> coarse place -> fine sub-CSR ---
  bucket_hist_kernel<<<CSB, 256, nbuckets * 4, stream>>>(
      ev, ec, partial, n_edges, n_vars, nbuckets);

  // weight pre-conversion: all four sets, ONE launch
  {
    int total = 2 * R * 512 + 1024;
    wcvt_all_kernel<<<(total + 255) / 256, 256, 0, stream>>>(
        W_v2c, wh_v2c, W_c2v, wh_c2v, W_ve2, wh_ve2, W_ce2, wh_ce2, R * 512);
  }

  scan_blocks_kernel<<<nb2, 256, 0, stream>>>(partial, scanned, bsums, nP);
  scan_sums_kernel<<<1, 256, 0, stream>>>(bsums, nb2);
  scan_add_kernel<<<nb2, 256, 0, stream>>>(scanned, bsums, nP, 2 * n_edges);

  bucket_place_kernel<<<CSB, 256, nbuckets * 4, stream>>>(
      ev, ec, scanned, keypay, n_edges, n_vars, nbuckets);
  csr_fine_kernel<<<nbuckets, 256, 0, stream>>>(
      keypay, scanned, rp, esrc,
      h_var + (size_t)n_vars * 64, h_con + (size_t)n_cons * 64,
      n_nodes, nbuckets, 2 * n_edges);

  // encoders AFTER the build (their outputs host the build scratch)
  encoder_mfma_kernel<7><<<rowgrid16(n_vars), 256, 0, stream>>>(
      vf, W_ve1, b_ve1, wh_ve2, b_ve2, h_var, n_vars);
  encoder_mfma_kernel<5><<<rowgrid16(n_cons), 256, 0, stream>>>(
      cf, W_ce1, b_ce1, wh_ce2, b_ce2, h_con, n_cons);

  for (int r = 0; r < R; ++r) {
    fused_mfma_kernel<false><<<rowgrid16(n_cons), 256, 0, stream>>>(
        h_con, h_var, rp + n_vars, esrc,
        wh_v2c + (size_t)r * 512, b_v2c + (size_t)r * 64,
        nullptr, nullptr, nullptr, n_cons, n_vars);
    if (r == R - 1) {
      fused_mfma_kernel<true><<<rowgrid16(n_vars), 256, 0, stream>>>(
          h_var, h_con, rp, esrc,
          wh_c2v + (size_t)r * 512, b_c2v + (size_t)r * 64,
          W_ro, b_ro, (float*)d_out, n_vars, n_cons);
    } else {
      fused_mfma_kernel<false><<<rowgrid16(n_vars), 256, 0, stream>>>(
          h_var, h_con, rp, esrc,
          wh_c2v + (size_t)r * 512, b_c2v + (size_t)r * 64,
          nullptr, nullptr, nullptr, n_vars, n_cons);
    }
  }
}